// Round 6
// baseline (64.760 us; speedup 1.0000x reference)
//
#include <hip/hip_runtime.h>

// Depth-4 path signature, C=10, L=64, B=2048.
// R5: k-split lane-local form. Two lanes per (i,j) pair: lane h owns
// k in {5h..5h+4}; per-lane state = s3 half (5) + s4 half (50 floats) ->
// fits in VGPRs under the 128 cap (R3/R4's 100-float s4 forced AGPR
// shadowing + accvgpr copies = 2x inst inflation at 20% occupancy).
// Block = 256 thr = 1 elem (lanes 0..199 active; p=t>>1, h=t&1).
// Horner Chen step (verified R0-R4):
//   u1=s1+di/4; v1=s1+di/3; w1=s1+di/2
//   u2=s2+u1*dj/3; v2=s2+v1*dj/2; s2+=w1*dj; s1+=di
//   u3[k]=s3[k]+u2*dk/2; s3[k]+=v2*dk; s4[k][l]+=u3[k]*dl
// dx row LDS layout (ROWP=20): [d0..d9, pad, pad, d5..d9, pad*3] so each
// lane's k-half pairs are 8B-aligned at row + h*12 (2 uniform addrs/wave).

typedef float f2 __attribute__((ext_vector_type(2)));

constexpr int C = 10;
constexpr int L = 64;
constexpr int NSTEP = L - 1;                   // 63
constexpr int OUTSZ = 10 + 100 + 1000 + 10000; // 11110
constexpr int ROWP = 20;

__global__ __launch_bounds__(256) void sig4_kernel(
    const float* __restrict__ x, float* __restrict__ out)
{
  const int t = threadIdx.x;

  __shared__ float dxs[NSTEP * ROWP];  // [63][20]
  __shared__ float pl[C * L];          // staged path (prologue only)

  const float* __restrict__ xb = x + (size_t)blockIdx.x * (C * L);
  for (int i = t; i < C * L; i += 256) pl[i] = xb[i];
  __syncthreads();
  for (int i = t; i < NSTEP * C; i += 256) {
    int s = i / C, c = i - s * C;
    float v = pl[c * L + s + 1] - pl[c * L + s];
    dxs[s * ROWP + c] = v;
    if (c >= 5) dxs[s * ROWP + 7 + c] = v;   // 12 + (c-5)
  }
  __syncthreads();

  const int p = (t < 200) ? (t >> 1) : 0;    // pair index 0..99 (clamped)
  const int hh = t & 1;                      // k-half
  const int ii = p / 10;
  const int jj = p - ii * 10;

  float s1 = 0.f, s2 = 0.f;
  f2 s3p0 = {0.f, 0.f}, s3p1 = {0.f, 0.f};
  float s34 = 0.f;
  f2 s4[25];                                 // [kk][m]: k=5h+kk, l=2m,2m+1
  #pragma unroll
  for (int m = 0; m < 25; ++m) s4[m] = f2{0.f, 0.f};

  for (int s = 0; s < NSTEP; ++s) {
    const float* row = dxs + s * ROWP;
    const f2* rp = (const f2*)row;           // uniform broadcast pairs
    f2 dl[5];
    dl[0] = rp[0]; dl[1] = rp[1]; dl[2] = rp[2]; dl[3] = rp[3]; dl[4] = rp[4];
    const float* kb = row + hh * 12;         // k-half (2 uniform addrs)
    f2 dk01 = *(const f2*)kb;
    f2 dk23 = *(const f2*)(kb + 2);
    float dk4 = kb[4];
    float di = row[ii];                      // 10 banks, conflict-free
    float dj = row[jj];

    float u1 = fmaf(di, 0.25f, s1);
    float v1 = fmaf(di, (1.f / 3.f), s1);
    float w1 = fmaf(di, 0.5f, s1);
    float u2 = fmaf(u1, dj * (1.f / 3.f), s2);
    float v2 = fmaf(v1, dj * 0.5f, s2);
    s2 = fmaf(w1, dj, s2);
    s1 += di;

    float u2h = u2 * 0.5f;
    f2 u2v = {u2h, u2h};
    f2 v2v = {v2, v2};
    f2 u3p0 = __builtin_elementwise_fma(u2v, dk01, s3p0);
    f2 u3p1 = __builtin_elementwise_fma(u2v, dk23, s3p1);
    float u34 = fmaf(u2h, dk4, s34);
    s3p0 = __builtin_elementwise_fma(v2v, dk01, s3p0);
    s3p1 = __builtin_elementwise_fma(v2v, dk23, s3p1);
    s34 = fmaf(v2, dk4, s34);

    float u3s[5] = {u3p0.x, u3p0.y, u3p1.x, u3p1.y, u34};
    #pragma unroll
    for (int kk = 0; kk < 5; ++kk) {
      f2 ub = {u3s[kk], u3s[kk]};
      #pragma unroll
      for (int m = 0; m < 5; ++m)
        s4[kk * 5 + m] = __builtin_elementwise_fma(ub, dl[m], s4[kk * 5 + m]);
    }
  }

  // ---- epilogue ----
  if (t < 200) {
    float* __restrict__ ob = out + (size_t)blockIdx.x * OUTSZ;
    if (hh == 0 && jj == 0) ob[ii] = s1;     // level 1
    if (hh == 0) ob[10 + p] = s2;            // level 2
    float* o3 = ob + 110 + p * 10 + hh * 5;  // level 3 (5 scalars)
    o3[0] = s3p0.x; o3[1] = s3p0.y; o3[2] = s3p1.x; o3[3] = s3p1.y; o3[4] = s34;
    float* o4 = ob + 1110 + p * 100 + hh * 50;  // level 4: 50 contiguous
    #pragma unroll
    for (int kk = 0; kk < 5; ++kk)
      #pragma unroll
      for (int m = 0; m < 5; ++m)
        *(f2*)(o4 + kk * 10 + 2 * m) = s4[kk * 5 + m];
  }
}

extern "C" void kernel_launch(void* const* d_in, const int* in_sizes, int n_in,
                              void* d_out, int out_size, void* d_ws, size_t ws_size,
                              hipStream_t stream) {
  const float* x = (const float*)d_in[0];
  float* out = (float*)d_out;
  const int batch = in_sizes[0] / (C * L);   // 2048
  sig4_kernel<<<dim3(batch), dim3(256), 0, stream>>>(x, out);
}

// Round 7
// 62.461 us; speedup vs baseline: 1.0368x; 1.0368x over previous
//
#include <hip/hip_runtime.h>

// Depth-4 path signature, C=10, L=64, B=2048.
// R6 = R5 (k-split lane-local, zero barriers in main loop) +
//  (1) __launch_bounds__(256,3): force combined VGPR+AGPR budget <=~170.
//      R5 showed occ 24% (= 2 waves/SIMD, ~256-reg footprint) despite
//      VGPR_Count=68 -> allocator was shadowing state in AGPRs.
//  (2) 3-step batched row loads: one LDS-latency exposure per 3 steps
//      (all row values in registers before the math).
// Ownership: lane pair p=t>>1 owns (i,j)=(p/10,p%10); half h=t&1 owns
// k in {5h..5h+4}: s3 half (5 fl) + s4 half (25 f2). Lanes 200..255 idle.
// Horner Chen step (verified R0-R5):
//   u1=s1+di/4; v1=s1+di/3; w1=s1+di/2
//   u2=s2+u1*dj/3; v2=s2+v1*dj/2; s2+=w1*dj; s1+=di
//   u3[k]=s3[k]+u2*dk/2; s3[k]+=v2*dk; s4[k][l]+=u3[k]*dl
// dx row LDS layout (ROWP=20): [d0..d9, pad, pad, d5..d9, pad*3]; k-half
// pairs 8B-aligned at row + h*12 (2 uniform addrs/wave, conflict-free).

typedef float f2 __attribute__((ext_vector_type(2)));

constexpr int C = 10;
constexpr int L = 64;
constexpr int NSTEP = L - 1;                   // 63 = 21*3
constexpr int OUTSZ = 10 + 100 + 1000 + 10000; // 11110
constexpr int ROWP = 20;

struct Row {
  f2 dl0, dl1, dl2, dl3, dl4;   // broadcast pairs d(2m),d(2m+1)
  f2 dk01, dk23;                // this lane's k-half
  float dk4, di, dj;
};

__device__ __forceinline__ void load_row(const float* __restrict__ row,
                                         int ii, int jj, int koff, Row& r) {
  const f2* rp = (const f2*)row;
  r.dl0 = rp[0]; r.dl1 = rp[1]; r.dl2 = rp[2]; r.dl3 = rp[3]; r.dl4 = rp[4];
  const float* kb = row + koff;        // koff = h*12, 8B-aligned
  r.dk01 = *(const f2*)kb;
  r.dk23 = *(const f2*)(kb + 2);
  r.dk4 = kb[4];
  r.di = row[ii];                      // 10 banks, conflict-free
  r.dj = row[jj];
}

__global__ __launch_bounds__(256, 3) void sig4_kernel(
    const float* __restrict__ x, float* __restrict__ out)
{
  const int t = threadIdx.x;

  __shared__ float dxs[NSTEP * ROWP];  // [63][20]
  __shared__ float pl[C * L];          // staged path (prologue only)

  const float* __restrict__ xb = x + (size_t)blockIdx.x * (C * L);
  for (int i = t; i < C * L; i += 256) pl[i] = xb[i];
  __syncthreads();
  for (int i = t; i < NSTEP * C; i += 256) {
    int s = i / C, c = i - s * C;
    float v = pl[c * L + s + 1] - pl[c * L + s];
    dxs[s * ROWP + c] = v;
    if (c >= 5) dxs[s * ROWP + 7 + c] = v;   // duplicate upper half at 12..16
  }
  __syncthreads();

  const int p = (t < 200) ? (t >> 1) : 0;    // pair index, clamped for idles
  const int hh = t & 1;                      // k-half
  const int koff = hh * 12;
  const int ii = p / 10;
  const int jj = p - ii * 10;

  float s1 = 0.f, s2 = 0.f;
  f2 s3p0 = {0.f, 0.f}, s3p1 = {0.f, 0.f};
  float s34 = 0.f;
  f2 s4[25];                                 // [kk][m]: k=5h+kk, l=2m,2m+1
  #pragma unroll
  for (int m = 0; m < 25; ++m) s4[m] = f2{0.f, 0.f};

  auto step = [&](const Row& r) {
    float u1 = fmaf(r.di, 0.25f, s1);
    float v1 = fmaf(r.di, (1.f / 3.f), s1);
    float w1 = fmaf(r.di, 0.5f, s1);
    float u2 = fmaf(u1, r.dj * (1.f / 3.f), s2);
    float v2 = fmaf(v1, r.dj * 0.5f, s2);
    s2 = fmaf(w1, r.dj, s2);
    s1 += r.di;

    float u2h = u2 * 0.5f;
    f2 u2v = {u2h, u2h};
    f2 v2v = {v2, v2};
    f2 u3p0 = __builtin_elementwise_fma(u2v, r.dk01, s3p0);
    f2 u3p1 = __builtin_elementwise_fma(u2v, r.dk23, s3p1);
    float u34 = fmaf(u2h, r.dk4, s34);
    s3p0 = __builtin_elementwise_fma(v2v, r.dk01, s3p0);
    s3p1 = __builtin_elementwise_fma(v2v, r.dk23, s3p1);
    s34 = fmaf(v2, r.dk4, s34);

    float u3s[5] = {u3p0.x, u3p0.y, u3p1.x, u3p1.y, u34};
    f2 dl[5] = {r.dl0, r.dl1, r.dl2, r.dl3, r.dl4};
    #pragma unroll
    for (int kk = 0; kk < 5; ++kk) {
      f2 ub = {u3s[kk], u3s[kk]};
      #pragma unroll
      for (int m = 0; m < 5; ++m)
        s4[kk * 5 + m] = __builtin_elementwise_fma(ub, dl[m], s4[kk * 5 + m]);
    }
  };

  for (int sb = 0; sb < NSTEP; sb += 3) {
    const float* base = dxs + sb * ROWP;
    Row r0, r1, r2;
    load_row(base,            ii, jj, koff, r0);
    load_row(base + ROWP,     ii, jj, koff, r1);
    load_row(base + 2 * ROWP, ii, jj, koff, r2);
    step(r0);
    step(r1);
    step(r2);
  }

  // ---- epilogue: each lane stores its own slices (8B-aligned f2) ----
  if (t < 200) {
    float* __restrict__ ob = out + (size_t)blockIdx.x * OUTSZ;
    if (hh == 0 && jj == 0) ob[ii] = s1;     // level 1
    if (hh == 0) ob[10 + p] = s2;            // level 2
    float* o3 = ob + 110 + p * 10 + hh * 5;  // level 3 (5 scalars)
    o3[0] = s3p0.x; o3[1] = s3p0.y; o3[2] = s3p1.x; o3[3] = s3p1.y; o3[4] = s34;
    float* o4 = ob + 1110 + p * 100 + hh * 50;  // level 4: 50 contiguous
    #pragma unroll
    for (int kk = 0; kk < 5; ++kk)
      #pragma unroll
      for (int m = 0; m < 5; ++m)
        *(f2*)(o4 + kk * 10 + 2 * m) = s4[kk * 5 + m];
  }
}

extern "C" void kernel_launch(void* const* d_in, const int* in_sizes, int n_in,
                              void* d_out, int out_size, void* d_ws, size_t ws_size,
                              hipStream_t stream) {
  const float* x = (const float*)d_in[0];
  float* out = (float*)d_out;
  const int batch = in_sizes[0] / (C * L);   // 2048
  sig4_kernel<<<dim3(batch), dim3(256), 0, stream>>>(x, out);
}